// Round 13
// baseline (2286.674 us; speedup 1.0000x reference)
//
#include <hip/hip_runtime.h>
#include <hip/hip_cooperative_groups.h>
#include <hip/hip_bf16.h>

namespace cg = cooperative_groups;

#define T_STEPS 512
#define UDIM    512
#define SENT    0xFFFFFFFFu

typedef __attribute__((ext_vector_type(8))) __bf16 bf16x8;
typedef __attribute__((ext_vector_type(4))) float  f32x4;

// Round-13: batch-split software pipeline. 64 WGs = 2dir x 32 slices (16 cols).
// Batch rows split into group A (0-15) and B (16-31) = two INDEPENDENT
// recurrence chains interleaved per iteration:
//   [barrier; MFMA_A; barrier; gates_A] -> wait+check L_B(t) -> store h_A(t+1)
//   -> stage B -> issue L_A'(t+1) -> [barrier; MFMA_B; barrier; gates_B]
//   -> wait+check L_A'(t+1) -> store h_B(t+1) -> stage A -> poison buf[t%3]
//   -> issue L_B(t+1)
// Each chain's exchange RT hides under the other chain's compute phase.
// Same total FLOPs as r7 (unlike r11's direction merge). Weights (R,K)
// register-resident, SHARED by both groups (wave = gate x K-half, 9 MFMA
// 16x16x32 per group phase, M=16 = full tile).
// Poison: single site at iter end, after check of h_A(t+1) — observing
// h_A(t+1) from every producer implies all reads of buf[t%3] completed
// (each producer's h_A(t+1) store follows its stage of BOTH halves of h(t)).
// Poison ≺ next-iter vmcnt(0) ≺ our h_A(t+2) store preserves r7's
// LLC-serialization visibility proof. Sentinel semantics unchanged.
//
// ws layout (bytes): dir d, buffer b in [0,3): (d*3+b)*32768,
// each [32 rows][512 bf16 cols]. Total 192KB.

__global__ __launch_bounds__(512, 1)
void lstm_bidir_kernel(const float* __restrict__ x,
                       const float* __restrict__ Kf, const float* __restrict__ Rf,
                       const float* __restrict__ bfp,
                       const float* __restrict__ Kb, const float* __restrict__ Rb,
                       const float* __restrict__ bbp,
                       float* __restrict__ out, float* __restrict__ ws)
{
    __shared__ __align__(16) unsigned char hAls[16 * 1024];   // 16KB group-A h tile
    __shared__ __align__(16) unsigned char hBls[16 * 1024];   // 16KB group-B h tile
    __shared__ __align__(16) unsigned char xls[32 * 128];     // 4KB x tile (both groups)
    __shared__ __align__(16) float zA[32 * 68];               // kh-partials group A
    __shared__ __align__(16) float zB[32 * 68];               // kh-partials group B
    __shared__ float cbuf[512];                               // c: [0,256)=A, [256,512)=B
    __shared__ float bsh[64];

    const int tid = threadIdx.x;
    const int wg  = blockIdx.x;
    const int dir = wg >> 5, slice = wg & 31;
    const int colbase = slice * 16;

    const float* Kg = dir ? Kb : Kf;
    const float* Rg = dir ? Rb : Rf;
    const float* bg = dir ? bbp : bfp;

    unsigned char* wsb = (unsigned char*)ws;
    unsigned char* dirbase = wsb + (size_t)dir * 98304;

    // ---- init: buf0 = h(0) = 0, buf1/buf2 = SENT; both dirs ----
    {
        int g = wg * 512 + tid;
        ((unsigned int*)wsb)[g] = (((g >> 13) % 3) == 0) ? 0u : SENT;
        int g2 = g + 32768;
        if (g2 < 49152)
            ((unsigned int*)wsb)[g2] = (((g2 >> 13) % 3) == 0) ? 0u : SENT;
    }
    if (tid < 64) bsh[tid] = bg[(tid >> 4) * 512 + colbase + (tid & 15)];
    cbuf[tid] = 0.f;

    // ---- wave roles + register-resident B-fragments (shared A/B groups) ----
    const int lane = tid & 63;
    const int w    = tid >> 6;
    const int gate = w & 3;
    const int kh   = w >> 2;        // K-half 0..1 (R: 256 each, x: 32 each)
    const int bn   = lane & 15;
    const int kg   = lane >> 4;     // 0..3
    const int gcol = gate * 512 + colbase + bn;

    bf16x8 breg[9];
    #pragma unroll
    for (int s = 0; s < 8; ++s) {
        const int k0 = kh * 256 + s * 32 + kg * 8;
        bf16x8 v;
        #pragma unroll
        for (int e = 0; e < 8; ++e) v[e] = (__bf16)Rg[(size_t)(k0 + e) * 2048 + gcol];
        breg[s] = v;
    }
    {
        const int k0 = kh * 32 + kg * 8;
        bf16x8 v;
        #pragma unroll
        for (int e = 0; e < 8; ++e) v[e] = (__bf16)Kg[(size_t)(k0 + e) * 2048 + gcol];
        breg[8] = v;
    }

    // ---- x(0) into xls; hAls = zeros (h_A(0) = 0) ----
    if (tid < 256) {
        const int t0 = dir ? (T_STEPS - 1) : 0;
        int b = tid >> 3, m = tid & 7;
        const float4* xg = (const float4*)(x + (size_t)b * (T_STEPS * 64) + (size_t)t0 * 64 + m * 8);
        float4 v0 = xg[0], v1 = xg[1];
        unsigned int p0 = ((unsigned int)__builtin_bit_cast(unsigned short, (__bf16)v0.x)) |
                          ((unsigned int)__builtin_bit_cast(unsigned short, (__bf16)v0.y) << 16);
        unsigned int p1 = ((unsigned int)__builtin_bit_cast(unsigned short, (__bf16)v0.z)) |
                          ((unsigned int)__builtin_bit_cast(unsigned short, (__bf16)v0.w) << 16);
        unsigned int p2 = ((unsigned int)__builtin_bit_cast(unsigned short, (__bf16)v1.x)) |
                          ((unsigned int)__builtin_bit_cast(unsigned short, (__bf16)v1.y) << 16);
        unsigned int p3 = ((unsigned int)__builtin_bit_cast(unsigned short, (__bf16)v1.z)) |
                          ((unsigned int)__builtin_bit_cast(unsigned short, (__bf16)v1.w) << 16);
        *(uint4*)(xls + b * 128 + ((m ^ (b & 7)) << 4)) = make_uint4(p0, p1, p2, p3);
    }
    {
        uint4 z4 = make_uint4(0, 0, 0, 0);
        *(uint4*)(hAls + tid * 32)      = z4;
        *(uint4*)(hAls + tid * 32 + 16) = z4;
    }

    cg::grid_group grid = cg::this_grid();
    grid.sync();   // init visible device-wide (once)

    const int srow = tid >> 5;       // staging row 0..15 (local)
    const int sc   = tid & 31;       // chunk base 0..31
    const int sinv = srow & 7;
    const int gr   = tid >> 4;       // gates row (tid<256): 0..15
    const int gc   = tid & 15;       // gates col

    float h_keepA = 0.f, h_keepB = 0.f;
    float4 xv0, xv1;
    uint4 ra0, ra1, rb0, rb1;

    // prologue: issue L_B(0) from buf0 B-rows (zeros)
    {
        const unsigned char* src = dirbase + (size_t)(16 + srow) * 1024;
        asm volatile("global_load_dwordx4 %0, %1, off sc0 sc1" : "=&v"(rb0) : "v"(src + sc * 16) : "memory");
        asm volatile("global_load_dwordx4 %0, %1, off sc0 sc1" : "=&v"(rb1) : "v"(src + (sc + 32) * 16) : "memory");
    }

    #pragma unroll 1
    for (int t = 0; t < T_STEPS; ++t) {
        __syncthreads();   // hAls(t) + xls(t) ready

        // ---- MFMA_A ----
        {
            const int r = lane & 15, inv = r & 7;
            f32x4 a0 = {0.f,0.f,0.f,0.f}, a1 = {0.f,0.f,0.f,0.f};
            #pragma unroll
            for (int s = 0; s < 8; ++s) {
                int ch = kh * 32 + s * 4 + kg;
                bf16x8 a = *(const bf16x8*)(hAls + r * 1024 + ((ch ^ inv) << 4));
                if (s & 1) a1 = __builtin_amdgcn_mfma_f32_16x16x32_bf16(a, breg[s], a1, 0, 0, 0);
                else       a0 = __builtin_amdgcn_mfma_f32_16x16x32_bf16(a, breg[s], a0, 0, 0, 0);
            }
            {
                int chx = kh * 4 + kg;
                bf16x8 ax = *(const bf16x8*)(xls + r * 128 + ((chx ^ inv) << 4));
                a0 = __builtin_amdgcn_mfma_f32_16x16x32_bf16(ax, breg[8], a0, 0, 0, 0);
            }
            #pragma unroll
            for (int j = 0; j < 4; ++j)
                zA[(kh * 16 + kg * 4 + j) * 68 + gate * 16 + bn] = a0[j] + a1[j];
        }
        __syncthreads();

        // ---- gates_A: h for group A, time t ----
        if (tid < 256) {
            float zi = zA[gr * 68 +      gc] + zA[(16 + gr) * 68 +      gc] + bsh[gc];
            float zf = zA[gr * 68 + 16 + gc] + zA[(16 + gr) * 68 + 16 + gc] + bsh[16 + gc];
            float zg = zA[gr * 68 + 32 + gc] + zA[(16 + gr) * 68 + 32 + gc] + bsh[32 + gc];
            float zo = zA[gr * 68 + 48 + gc] + zA[(16 + gr) * 68 + 48 + gc] + bsh[48 + gc];
            float gi = 1.f / (1.f + __expf(-zi));
            float gf = 1.f / (1.f + __expf(-zf));
            float gg = zg / (1.f + __expf(-zg));
            float go = 1.f / (1.f + __expf(-zo));
            float cv = gf * cbuf[tid] + gi * gg;
            cbuf[tid] = cv;
            h_keepA = go * (cv / (1.f + __expf(-cv)));
        }

        // ---- wait + sentinel-check L_B(t) (issued one compute-phase ago) ----
        asm volatile("s_waitcnt vmcnt(0)" ::: "memory");
        __builtin_amdgcn_sched_barrier(0);
        {
            const unsigned char* src = dirbase + (size_t)(t % 3) * 32768 + (size_t)(16 + srow) * 1024;
            unsigned bad = (rb0.x == SENT) | (rb0.y == SENT) | (rb0.z == SENT) | (rb0.w == SENT)
                         | (rb1.x == SENT) | (rb1.y == SENT) | (rb1.z == SENT) | (rb1.w == SENT);
            while (bad) {
                asm volatile("global_load_dwordx4 %0, %1, off sc0 sc1" : "=&v"(rb0) : "v"(src + sc * 16) : "memory");
                asm volatile("global_load_dwordx4 %0, %1, off sc0 sc1" : "=&v"(rb1) : "v"(src + (sc + 32) * 16) : "memory");
                asm volatile("s_waitcnt vmcnt(0)" ::: "memory");
                __builtin_amdgcn_sched_barrier(0);
                bad = (rb0.x == SENT) | (rb0.y == SENT) | (rb0.z == SENT) | (rb0.w == SENT)
                    | (rb1.x == SENT) | (rb1.y == SENT) | (rb1.z == SENT) | (rb1.w == SENT);
            }
        }

        // ---- store h_A(t+1)  (poison(t-1) drained by the vmcnt above) ----
        if (tid < 256) {
            unsigned short hu = __builtin_bit_cast(unsigned short, (__bf16)h_keepA);
            int other = __shfl_xor((int)hu, 1);
            if ((gc & 1) == 0) {
                unsigned int packed = (unsigned int)hu | ((unsigned int)(unsigned short)other << 16);
                unsigned int* dst = (unsigned int*)(dirbase + (size_t)((t + 1) % 3) * 32768)
                                    + gr * 256 + ((colbase + gc) >> 1);
                __hip_atomic_store(dst, packed, __ATOMIC_RELAXED, __HIP_MEMORY_SCOPE_AGENT);
            }
        }

        // ---- stage B into LDS_B ----
        *(uint4*)(hBls + srow * 1024 + ((sc        ^ sinv) << 4)) = rb0;
        *(uint4*)(hBls + srow * 1024 + (((sc + 32) ^ sinv) << 4)) = rb1;

        // ---- out-B(t-1) ----
        if (t > 0 && tid < 256) {
            int txp = dir ? (T_STEPS - t) : (t - 1);
            out[(size_t)(16 + gr) * (T_STEPS * 2 * UDIM) + (size_t)txp * (2 * UDIM)
                + dir * UDIM + colbase + gc] = h_keepB;
        }

        // ---- issue L_A'(t+1); x(t+1) load ----
        if (t + 1 < T_STEPS) {
            const unsigned char* src = dirbase + (size_t)((t + 1) % 3) * 32768 + (size_t)srow * 1024;
            asm volatile("global_load_dwordx4 %0, %1, off sc0 sc1" : "=&v"(ra0) : "v"(src + sc * 16) : "memory");
            asm volatile("global_load_dwordx4 %0, %1, off sc0 sc1" : "=&v"(ra1) : "v"(src + (sc + 32) * 16) : "memory");
            if (tid < 256) {
                const int tn = dir ? (T_STEPS - 2 - t) : (t + 1);
                int b = tid >> 3, m = tid & 7;
                const float4* xg = (const float4*)(x + (size_t)b * (T_STEPS * 64) + (size_t)tn * 64 + m * 8);
                xv0 = xg[0]; xv1 = xg[1];
            }
        }

        __syncthreads();   // hBls staged

        // ---- MFMA_B ----
        {
            const int r = lane & 15, inv = r & 7;
            f32x4 a0 = {0.f,0.f,0.f,0.f}, a1 = {0.f,0.f,0.f,0.f};
            #pragma unroll
            for (int s = 0; s < 8; ++s) {
                int ch = kh * 32 + s * 4 + kg;
                bf16x8 a = *(const bf16x8*)(hBls + r * 1024 + ((ch ^ inv) << 4));
                if (s & 1) a1 = __builtin_amdgcn_mfma_f32_16x16x32_bf16(a, breg[s], a1, 0, 0, 0);
                else       a0 = __builtin_amdgcn_mfma_f32_16x16x32_bf16(a, breg[s], a0, 0, 0, 0);
            }
            {
                int chx = kh * 4 + kg;
                int xr = 16 + r;   // (16+r)&7 == r&7
                bf16x8 ax = *(const bf16x8*)(xls + xr * 128 + ((chx ^ inv) << 4));
                a0 = __builtin_amdgcn_mfma_f32_16x16x32_bf16(ax, breg[8], a0, 0, 0, 0);
            }
            #pragma unroll
            for (int j = 0; j < 4; ++j)
                zB[(kh * 16 + kg * 4 + j) * 68 + gate * 16 + bn] = a0[j] + a1[j];
        }
        __syncthreads();

        // ---- gates_B + xls(t+1) write ----
        if (tid < 256) {
            float zi = zB[gr * 68 +      gc] + zB[(16 + gr) * 68 +      gc] + bsh[gc];
            float zf = zB[gr * 68 + 16 + gc] + zB[(16 + gr) * 68 + 16 + gc] + bsh[16 + gc];
            float zg = zB[gr * 68 + 32 + gc] + zB[(16 + gr) * 68 + 32 + gc] + bsh[32 + gc];
            float zo = zB[gr * 68 + 48 + gc] + zB[(16 + gr) * 68 + 48 + gc] + bsh[48 + gc];
            float gi = 1.f / (1.f + __expf(-zi));
            float gf = 1.f / (1.f + __expf(-zf));
            float gg = zg / (1.f + __expf(-zg));
            float go = 1.f / (1.f + __expf(-zo));
            float cv = gf * cbuf[256 + tid] + gi * gg;
            cbuf[256 + tid] = cv;
            h_keepB = go * (cv / (1.f + __expf(-cv)));
        }
        if (t + 1 < T_STEPS && tid < 256) {
            int b = tid >> 3, m = tid & 7;
            unsigned int p0 = ((unsigned int)__builtin_bit_cast(unsigned short, (__bf16)xv0.x)) |
                              ((unsigned int)__builtin_bit_cast(unsigned short, (__bf16)xv0.y) << 16);
            unsigned int p1 = ((unsigned int)__builtin_bit_cast(unsigned short, (__bf16)xv0.z)) |
                              ((unsigned int)__builtin_bit_cast(unsigned short, (__bf16)xv0.w) << 16);
            unsigned int p2 = ((unsigned int)__builtin_bit_cast(unsigned short, (__bf16)xv1.x)) |
                              ((unsigned int)__builtin_bit_cast(unsigned short, (__bf16)xv1.y) << 16);
            unsigned int p3 = ((unsigned int)__builtin_bit_cast(unsigned short, (__bf16)xv1.z)) |
                              ((unsigned int)__builtin_bit_cast(unsigned short, (__bf16)xv1.w) << 16);
            *(uint4*)(xls + b * 128 + ((m ^ (b & 7)) << 4)) = make_uint4(p0, p1, p2, p3);
        }

        // ---- end block: wait/check L_A'(t+1); store h_B; stage A; poison; out-A; issue L_B ----
        if (t + 1 < T_STEPS) {
            asm volatile("s_waitcnt vmcnt(0)" ::: "memory");
            __builtin_amdgcn_sched_barrier(0);
            {
                const unsigned char* src = dirbase + (size_t)((t + 1) % 3) * 32768 + (size_t)srow * 1024;
                unsigned bad = (ra0.x == SENT) | (ra0.y == SENT) | (ra0.z == SENT) | (ra0.w == SENT)
                             | (ra1.x == SENT) | (ra1.y == SENT) | (ra1.z == SENT) | (ra1.w == SENT);
                while (bad) {
                    asm volatile("global_load_dwordx4 %0, %1, off sc0 sc1" : "=&v"(ra0) : "v"(src + sc * 16) : "memory");
                    asm volatile("global_load_dwordx4 %0, %1, off sc0 sc1" : "=&v"(ra1) : "v"(src + (sc + 32) * 16) : "memory");
                    asm volatile("s_waitcnt vmcnt(0)" ::: "memory");
                    __builtin_amdgcn_sched_barrier(0);
                    bad = (ra0.x == SENT) | (ra0.y == SENT) | (ra0.z == SENT) | (ra0.w == SENT)
                        | (ra1.x == SENT) | (ra1.y == SENT) | (ra1.z == SENT) | (ra1.w == SENT);
                }
            }
            if (tid < 256) {
                unsigned short hu = __builtin_bit_cast(unsigned short, (__bf16)h_keepB);
                int other = __shfl_xor((int)hu, 1);
                if ((gc & 1) == 0) {
                    unsigned int packed = (unsigned int)hu | ((unsigned int)(unsigned short)other << 16);
                    unsigned int* dst = (unsigned int*)(dirbase + (size_t)((t + 1) % 3) * 32768)
                                        + (16 + gr) * 256 + ((colbase + gc) >> 1);
                    __hip_atomic_store(dst, packed, __ATOMIC_RELAXED, __HIP_MEMORY_SCOPE_AGENT);
                }
            }
            *(uint4*)(hAls + srow * 1024 + ((sc        ^ sinv) << 4)) = ra0;
            *(uint4*)(hAls + srow * 1024 + (((sc + 32) ^ sinv) << 4)) = ra1;
            // poison buf[t%3]: all 32 rows x own 16 cols (proof: h_A(t+1)
            // observed => all producers consumed both halves of h(t))
            if (tid < 256) {
                int prow = tid >> 3, dw = tid & 7;
                unsigned int* pp = (unsigned int*)(dirbase + (size_t)(t % 3) * 32768
                                                   + prow * 1024 + colbase * 2) + dw;
                __hip_atomic_store(pp, SENT, __ATOMIC_RELAXED, __HIP_MEMORY_SCOPE_AGENT);
            }
            if (tid < 256) {
                int tx = dir ? (T_STEPS - 1 - t) : t;
                out[(size_t)gr * (T_STEPS * 2 * UDIM) + (size_t)tx * (2 * UDIM)
                    + dir * UDIM + colbase + gc] = h_keepA;
            }
            {
                const unsigned char* src = dirbase + (size_t)((t + 1) % 3) * 32768 + (size_t)(16 + srow) * 1024;
                asm volatile("global_load_dwordx4 %0, %1, off sc0 sc1" : "=&v"(rb0) : "v"(src + sc * 16) : "memory");
                asm volatile("global_load_dwordx4 %0, %1, off sc0 sc1" : "=&v"(rb1) : "v"(src + (sc + 32) * 16) : "memory");
            }
        }
    }

    // epilogue: outputs for t = 511 (both groups)
    if (tid < 256) {
        int tx = dir ? 0 : (T_STEPS - 1);
        out[(size_t)gr * (T_STEPS * 2 * UDIM) + (size_t)tx * (2 * UDIM)
            + dir * UDIM + colbase + gc] = h_keepA;
        out[(size_t)(16 + gr) * (T_STEPS * 2 * UDIM) + (size_t)tx * (2 * UDIM)
            + dir * UDIM + colbase + gc] = h_keepB;
    }
}

extern "C" void kernel_launch(void* const* d_in, const int* in_sizes, int n_in,
                              void* d_out, int out_size, void* d_ws, size_t ws_size,
                              hipStream_t stream) {
    (void)in_sizes; (void)n_in; (void)out_size; (void)ws_size;
    const float* x  = (const float*)d_in[0];
    const float* Kf = (const float*)d_in[1];
    const float* Rf = (const float*)d_in[2];
    const float* bf = (const float*)d_in[3];
    const float* Kb = (const float*)d_in[4];
    const float* Rb = (const float*)d_in[5];
    const float* bb = (const float*)d_in[6];
    float* out = (float*)d_out;
    float* ws  = (float*)d_ws;

    void* args[] = {&x, &Kf, &Rf, &bf, &Kb, &Rb, &bb, &out, &ws};
    hipLaunchCooperativeKernel((const void*)lstm_bidir_kernel,
                               dim3(64), dim3(512), args, 0, stream);
}